// Round 1
// 490.006 us; speedup vs baseline: 1.1689x; 1.1689x over previous
//
#include <hip/hip_runtime.h>
#include <hip/hip_bf16.h>

#define D 128
typedef unsigned short u16;
typedef unsigned int u32;
typedef __attribute__((ext_vector_type(4))) unsigned int u32x4;

__device__ __forceinline__ float bf2f(u16 u) {
    return __uint_as_float(((u32)u) << 16);
}
__device__ __forceinline__ u16 f2bf(float f) {
    union { float f; u32 u; } a; a.f = f;
    u32 r = (a.u + 0x7FFF + ((a.u >> 16) & 1)) >> 16;   // RNE
    return (u16)r;
}
__device__ __forceinline__ float2 bf2x2(u32 v) {        // packed bf16 pair -> 2 floats
    float2 r;
    r.x = __uint_as_float(v << 16);
    r.y = __uint_as_float(v & 0xFFFF0000u);
    return r;
}
__device__ __forceinline__ u32 packbf2(float a, float b) {
    return (u32)f2bf(a) | ((u32)f2bf(b) << 16);
}
// flag-dependent raw-input access (epilogue / prep only)
__device__ __forceinline__ float ldIn(const void* p, size_t i, int isBf) {
    return isBf ? bf2f(((const u16*)p)[i]) : ((const float*)p)[i];
}
__device__ __forceinline__ void stOut(void* p, size_t i, float v, int isBf) {
    if (isBf) ((u16*)p)[i] = f2bf(v);
    else      ((float*)p)[i] = v;
}

// ---------------- dtype sniffer --------------------------------------------
__global__ void sniff_k(const u16* __restrict__ probe, int* __restrict__ flag) {
    int t = threadIdx.x;           // 64 threads
    u16 v = probe[2 * t];
    int ex = (v >> 7) & 0xFF;
    int sane = (ex == 0) || (ex >= 0x70 && ex <= 0x8A);
    unsigned long long m = __ballot(sane != 0);
    if (t == 0) *flag = (__popcll(m) >= 48) ? 1 : 0;
}

// ---------------- convert raw input -> canonical bf16 -----------------------
__global__ void convert_k(const void* __restrict__ src, u16* __restrict__ dst,
                          int n, const int* __restrict__ flagp) {
    int i = blockIdx.x * blockDim.x + threadIdx.x;
    int isBf = *flagp;
    if (i < n) dst[i] = isBf ? ((const u16*)src)[i] : f2bf(((const float*)src)[i]);
}

// ---------------- CSR build -------------------------------------------------
__global__ void zero_k(int* __restrict__ p, int n) {
    int i = blockIdx.x * blockDim.x + threadIdx.x;
    if (i < n) p[i] = 0;
}
__global__ void hist_k(const int* __restrict__ keys, int n, int nDst,
                       int* __restrict__ cntP1) {
    int i = blockIdx.x * blockDim.x + threadIdx.x;
    if (i < n) {
        int k = min(max(keys[i], 0), nDst - 1);
        atomicAdd(&cntP1[k + 1], 1);
    }
}
__global__ void copy_k(const int* __restrict__ src, int* __restrict__ dst, int n) {
    int i = blockIdx.x * blockDim.x + threadIdx.x;
    if (i < n) dst[i] = src[i];
}
// entity scatter: payload = tail | (rtype<<24), fully clamped at build
__global__ void scatter_e(const int* __restrict__ head, const int* __restrict__ tail,
                          const int* __restrict__ etyp, int n, int nDst, int nEnt,
                          int* __restrict__ pos, int* __restrict__ pack) {
    int i = blockIdx.x * blockDim.x + threadIdx.x;
    if (i < n) {
        int k = min(max(head[i], 0), nDst - 1);
        int p = atomicAdd(&pos[k], 1);
        if (p >= 0 && p < n) {
            int tl = min(max(tail[i], 0), nEnt - 1);
            int rt = min(max(etyp[i] - 1, 0), 9);
            pack[p] = tl | (rt << 24);
        }
    }
}
// user scatter: payload = (item, weight)
__global__ void scatter_u(const int* __restrict__ u_idx, const int* __restrict__ i_idx,
                          const void* __restrict__ iw, int n, int nDst, int nEnt,
                          int* __restrict__ pos, int* __restrict__ item,
                          float* __restrict__ wt, const int* __restrict__ flagp) {
    int i = blockIdx.x * blockDim.x + threadIdx.x;
    int isBf = *flagp;
    if (i < n) {
        int k = min(max(u_idx[i], 0), nDst - 1);
        int p = atomicAdd(&pos[k], 1);
        if (p >= 0 && p < n) {
            item[p] = min(max(i_idx[i], 0), nEnt - 1);
            wt[p] = ldIn(iw, i, isBf);
        }
    }
}

// ---------------- multi-block scan over buf[1..n] ---------------------------
__global__ __launch_bounds__(256) void block_sum_k(const int* __restrict__ buf, int n,
                                                   int* __restrict__ bsum) {
    __shared__ int waveTot[4];
    int b = blockIdx.x, t = threadIdx.x, lane = t & 63, wave = t >> 6;
    int idx = 1 + b * 1024 + t * 4;
    int s = 0;
    #pragma unroll
    for (int k = 0; k < 4; ++k)
        if (idx + k <= n) s += buf[idx + k];
    #pragma unroll
    for (int o = 32; o > 0; o >>= 1) s += __shfl_xor(s, o);
    if (lane == 0) waveTot[wave] = s;
    __syncthreads();
    if (t == 0) bsum[b] = waveTot[0] + waveTot[1] + waveTot[2] + waveTot[3];
}
__global__ void scan_bsums_k(int* __restrict__ bsum, int nb) {
    int t = threadIdx.x;   // 64 threads
    int v = (t < nb) ? bsum[t] : 0;
    int x = v;
    #pragma unroll
    for (int o = 1; o < 64; o <<= 1) {
        int y = __shfl_up(x, o);
        if (t >= o) x += y;
    }
    if (t < nb) bsum[t] = x - v;   // exclusive
}
__global__ __launch_bounds__(256) void block_scan_k(int* __restrict__ buf, int n,
                                                    const int* __restrict__ bsum) {
    __shared__ int waveTot[4];
    int b = blockIdx.x, t = threadIdx.x, lane = t & 63, wave = t >> 6;
    int idx = 1 + b * 1024 + t * 4;
    int v0 = 0, v1 = 0, v2 = 0, v3 = 0;
    if (idx     <= n) v0 = buf[idx];
    if (idx + 1 <= n) v1 = buf[idx + 1];
    if (idx + 2 <= n) v2 = buf[idx + 2];
    if (idx + 3 <= n) v3 = buf[idx + 3];
    int s = v0 + v1 + v2 + v3;
    int x = s;
    #pragma unroll
    for (int o = 1; o < 64; o <<= 1) {
        int y = __shfl_up(x, o);
        if (lane >= o) x += y;
    }
    if (lane == 63) waveTot[wave] = x;
    __syncthreads();
    int off = bsum[b];
    for (int wv = 0; wv < wave; ++wv) off += waveTot[wv];
    int r0 = off + (x - s) + v0;
    int r1 = r0 + v1;
    int r2 = r1 + v2;
    int r3 = r2 + v3;
    if (idx     <= n) buf[idx]     = r0;
    if (idx + 1 <= n) buf[idx + 1] = r1;
    if (idx + 2 <= n) buf[idx + 2] = r2;
    if (idx + 3 <= n) buf[idx + 3] = r3;
}

// ---------------- P = E @ W_Q via MFMA (bf16 in, bf16 out) ------------------
#define GEMM_ROWS 64
#define WT_STRIDE 136   // u16: 68-dword lane stride -> 2-way bank alias (free)
typedef __attribute__((ext_vector_type(8))) short bf16x8;
typedef __attribute__((ext_vector_type(4))) float f32x4;

__global__ __launch_bounds__(256) void gemm_P3(const u16* __restrict__ E,
                                               const u16* __restrict__ WQ,
                                               u16* __restrict__ P, int nRows) {
    __shared__ u16 sWT[D * WT_STRIDE];   // 34 KiB, W transposed: sWT[c][k]
    int t = threadIdx.x;
    for (int i = t; i < D * D; i += 256) {
        int k = i >> 7, c = i & 127;     // WQ[k][c] coalesced read
        sWT[c * WT_STRIDE + k] = WQ[i];
    }
    __syncthreads();
    int wave = t >> 6, lane = t & 63;
    int m = lane & 15, quad = lane >> 4;
    int row0 = blockIdx.x * GEMM_ROWS + wave * 16;
    int rowA = min(row0 + m, nRows - 1);
    const u16* erow = E + (size_t)rowA * D;
    bf16x8 afrag[4];
    #pragma unroll
    for (int ks = 0; ks < 4; ++ks)
        afrag[ks] = *(const bf16x8*)(erow + ks * 32 + quad * 8);
    #pragma unroll
    for (int ct = 0; ct < 8; ++ct) {
        f32x4 acc = {0.f, 0.f, 0.f, 0.f};
        const u16* wcol = sWT + (ct * 16 + m) * WT_STRIDE + quad * 8;
        #pragma unroll
        for (int ks = 0; ks < 4; ++ks) {
            bf16x8 bfrag = *(const bf16x8*)(wcol + ks * 32);
            acc = __builtin_amdgcn_mfma_f32_16x16x32_bf16(afrag[ks], bfrag, acc, 0, 0, 0);
        }
        #pragma unroll
        for (int reg = 0; reg < 4; ++reg) {
            int r = row0 + quad * 4 + reg;
            if (r < nRows) P[(size_t)r * D + ct * 16 + m] = f2bf(acc[reg]);
        }
    }
}

// ---------------- fused attention + aggregate + l2norm (+ mean epilogue) ----
// One wave per entity, FOUR edges in flight per iteration:
//   edge slot es = lane>>4 (0..3), sub-lane g = lane&15 holds dims [8g..8g+7]
//   (one dwordx4 = 16B per lane). Head of dims: g<8 -> head 0, g>=8 -> head 1.
// Score allreduce = 3 shfl_xor steps (1,2,4) within the 8-lane head group
// (vs 5 steps/edge before); exp2/broadcast/loop control amortize 4x.
// Softmax stays shift-free (|s| << 80 => exp2 exact-shift-invariant).
// Final 2-step cross-slot reduce (xor 16,32) merges the 4 partial sums.
__global__ __launch_bounds__(256) void entity_agg4(
    const u16* __restrict__ P, const u16* __restrict__ eCur,
    const u16* __restrict__ relb, const int* __restrict__ e_off,
    const int* __restrict__ e_pack, void* __restrict__ eOut,
    const u32* __restrict__ e0b, int finalMode, size_t outElemOff,
    int nEnt, const int* __restrict__ flagp) {
    // rel rows padded to 17 uint4 (272B): rt rows land on shifted bank groups
    __shared__ __align__(16) u32 sRel[10 * 68];   // 2.7 KiB
    int tid = threadIdx.x;
    {
        const u32* R = (const u32*)relb;
        for (int i = tid; i < 640; i += 256)
            sRel[(i >> 6) * 68 + (i & 63)] = R[i];
    }
    __syncthreads();
    int wid = (blockIdx.x * blockDim.x + tid) >> 6;
    int lane = tid & 63;
    if (wid >= nEnt) return;
    int es = lane >> 4, g = lane & 15;
    const u32x4* P4 = (const u32x4*)P;
    const u32x4* E4 = (const u32x4*)eCur;
    const float SC = 0.125f * 1.44269504f;   // /sqrt(64) folded with log2(e)
    float q[8];
    {
        u32x4 qa = P4[(size_t)wid * 16 + g];
        #pragma unroll
        for (int k = 0; k < 4; ++k) {
            float2 f = bf2x2(qa[k]);
            q[2 * k]     = f.x * SC;          // fold scale into q once
            q[2 * k + 1] = f.y * SC;
        }
    }
    float l = 0.f, a[8];
    #pragma unroll
    for (int k = 0; k < 8; ++k) a[k] = 0.f;
    int s = e_off[wid], e = e_off[wid + 1];
    for (int j0 = s; j0 < e; j0 += 64) {
        int B = min(64, e - j0);
        int pk = (lane < B) ? e_pack[j0 + lane] : 0;
        int pv = __shfl(pk, es);             // slot es' first edge (bpermute)
        size_t off = (size_t)(pv & 0xFFFFFF) * 16 + g;
        u32x4 ptv = P4[off];
        u32x4 evv = E4[off];
        for (int j = 0; j < B; j += 4) {
            u32x4 cpt = ptv, cev = evv;
            int cpv = pv;
            bool act = (j + es) < B;
            if (j + 4 < B) {                 // prefetch next 4 edges' rows
                pv = __shfl(pk, j + 4 + es); // idx <= 63 (j mult of 4, j+4<B<=64)
                off = (size_t)(pv & 0xFFFFFF) * 16 + g;
                ptv = P4[off];
                evv = E4[off];
            }
            int rt = (int)((u32)cpv >> 24);  // clamped to [0,9] at build
            u32x4 crr = *(const u32x4*)(sRel + rt * 68 + g * 4);
            float vv[8];
            float prod = 0.f;
            #pragma unroll
            for (int k = 0; k < 4; ++k) {
                float2 rr  = bf2x2(crr[k]);
                float2 pt  = bf2x2(cpt[k]);
                float2 evf = bf2x2(cev[k]);
                prod = fmaf(q[2 * k]     * rr.x, pt.x, prod);
                prod = fmaf(q[2 * k + 1] * rr.y, pt.y, prod);
                vv[2 * k]     = evf.x * rr.x;
                vv[2 * k + 1] = evf.y * rr.y;
            }
            #pragma unroll
            for (int o = 4; o > 0; o >>= 1) prod += __shfl_xor(prod, o);
            float p = act ? exp2f(prod) : 0.f;
            l += p;
            #pragma unroll
            for (int k = 0; k < 8; ++k) a[k] = fmaf(p, vv[k], a[k]);
        }
    }
    // merge the 4 edge-slot partials (head halves stay separate: g&8 invariant)
    #pragma unroll
    for (int o = 16; o <= 32; o <<= 1) {
        l += __shfl_xor(l, o);
        #pragma unroll
        for (int k = 0; k < 8; ++k) a[k] += __shfl_xor(a[k], o);
    }
    float rl = (l > 0.f) ? 1.f / l : 0.f;
    float w8[8];
    float ss = 0.f;
    #pragma unroll
    for (int k = 0; k < 8; ++k) {
        w8[k] = a[k] * rl;
        ss = fmaf(w8[k], w8[k], ss);
    }
    #pragma unroll
    for (int o = 8; o > 0; o >>= 1) ss += __shfl_xor(ss, o);
    float inv = 1.f / fmaxf(sqrtf(ss), 1e-12f);
    #pragma unroll
    for (int k = 0; k < 8; ++k) w8[k] *= inv;
    if (lane >= 16) return;                  // groups identical; group 0 stores
    if (finalMode) {
        int isBf = *flagp;
        const float k3 = 1.0f / 3.0f;
        float r[8];
        u32x4 t0 = ((const u32x4*)e0b)[(size_t)wid * 16 + g];   // eeb input
        u32x4 t1 = E4[(size_t)wid * 16 + g];                    // eL1
        #pragma unroll
        for (int k = 0; k < 4; ++k) {
            float2 f0 = bf2x2(t0[k]);
            float2 f1 = bf2x2(t1[k]);
            r[2 * k]     = (f0.x + f1.x + w8[2 * k]) * k3;
            r[2 * k + 1] = (f0.y + f1.y + w8[2 * k + 1]) * k3;
        }
        size_t be = outElemOff + (size_t)wid * 128 + (size_t)g * 8;
        if (isBf) {
            u32x4 o;
            o[0] = packbf2(r[0], r[1]); o[1] = packbf2(r[2], r[3]);
            o[2] = packbf2(r[4], r[5]); o[3] = packbf2(r[6], r[7]);
            *(u32x4*)((u16*)eOut + be) = o;          // be*2 bytes, 16B aligned
        } else {
            *(float4*)((float*)eOut + be)     = make_float4(r[0], r[1], r[2], r[3]);
            *(float4*)((float*)eOut + be + 4) = make_float4(r[4], r[5], r[6], r[7]);
        }
    } else {
        u32x4 o;
        o[0] = packbf2(w8[0], w8[1]); o[1] = packbf2(w8[2], w8[3]);
        o[2] = packbf2(w8[4], w8[5]); o[3] = packbf2(w8[6], w8[7]);
        ((u32x4*)eOut)[(size_t)wid * 16 + g] = o;
    }
}

// ---------------- user aggregation (4 items/iter, 2-deep prefetch) ----------
// Same 16-lane-per-item layout. Staged weights are 0 past B, so invalid
// slots self-mask (shfl idx never exceeds 63: j mult of 4, j+8<B<=64).
__global__ __launch_bounds__(256) void user_agg4(
    const u16* __restrict__ eCur, const int* __restrict__ u_off,
    const int* __restrict__ u_item, const float* __restrict__ u_wt,
    float* __restrict__ usum, const void* __restrict__ ueRaw,
    void* __restrict__ outU, int finalMode, int nU,
    const int* __restrict__ flagp) {
    int wid = (blockIdx.x * blockDim.x + threadIdx.x) >> 6;
    int lane = threadIdx.x & 63;
    if (wid >= nU) return;
    int es = lane >> 4, g = lane & 15;
    const u32x4* E4 = (const u32x4*)eCur;
    float a[8];
    #pragma unroll
    for (int k = 0; k < 8; ++k) a[k] = 0.f;
    int s = u_off[wid], e = u_off[wid + 1];
    for (int j0 = s; j0 < e; j0 += 64) {
        int B = min(64, e - j0);
        int it = (lane < B) ? u_item[j0 + lane] : 0;
        float wv = (lane < B) ? u_wt[j0 + lane] : 0.f;
        int i0 = __shfl(it, es);
        float w0 = __shfl(wv, es);
        u32x4 ev0 = E4[(size_t)i0 * 16 + g];
        u32x4 ev1 = ev0;
        float w1 = 0.f;
        if (B > 4) {
            int i1 = __shfl(it, 4 + es);
            w1 = __shfl(wv, 4 + es);
            ev1 = E4[(size_t)i1 * 16 + g];
        }
        for (int j = 0; j < B; j += 4) {
            u32x4 cur = ev0; float wc = w0;
            ev0 = ev1; w0 = w1;
            if (j + 8 < B) {                 // keep 2 iterations in flight
                int nx = __shfl(it, j + 8 + es);
                w1 = __shfl(wv, j + 8 + es);
                ev1 = E4[(size_t)nx * 16 + g];
            }
            #pragma unroll
            for (int k = 0; k < 4; ++k) {
                float2 f = bf2x2(cur[k]);
                a[2 * k]     = fmaf(wc, f.x, a[2 * k]);
                a[2 * k + 1] = fmaf(wc, f.y, a[2 * k + 1]);
            }
        }
    }
    #pragma unroll
    for (int o = 16; o <= 32; o <<= 1) {
        #pragma unroll
        for (int k = 0; k < 8; ++k) a[k] += __shfl_xor(a[k], o);
    }
    if (lane >= 16) return;
    size_t base = (size_t)wid * 128 + (size_t)g * 8;
    if (finalMode) {
        int isBf = *flagp;
        const float k3 = 1.0f / 3.0f;
        float4 u0 = ((const float4*)usum)[(size_t)wid * 32 + 2 * g];
        float4 u1 = ((const float4*)usum)[(size_t)wid * 32 + 2 * g + 1];
        float r[8];
        if (isBf) {
            u32x4 t = *(const u32x4*)((const u16*)ueRaw + base);
            #pragma unroll
            for (int k = 0; k < 4; ++k) {
                float2 f = bf2x2(t[k]);
                r[2 * k] = f.x; r[2 * k + 1] = f.y;
            }
        } else {
            float4 f0 = *(const float4*)((const float*)ueRaw + base);
            float4 f1 = *(const float4*)((const float*)ueRaw + base + 4);
            r[0] = f0.x; r[1] = f0.y; r[2] = f0.z; r[3] = f0.w;
            r[4] = f1.x; r[5] = f1.y; r[6] = f1.z; r[7] = f1.w;
        }
        float o0 = (r[0] + u0.x + a[0]) * k3;
        float o1 = (r[1] + u0.y + a[1]) * k3;
        float o2 = (r[2] + u0.z + a[2]) * k3;
        float o3 = (r[3] + u0.w + a[3]) * k3;
        float o4 = (r[4] + u1.x + a[4]) * k3;
        float o5 = (r[5] + u1.y + a[5]) * k3;
        float o6 = (r[6] + u1.z + a[6]) * k3;
        float o7 = (r[7] + u1.w + a[7]) * k3;
        if (isBf) {
            u32x4 o;
            o[0] = packbf2(o0, o1); o[1] = packbf2(o2, o3);
            o[2] = packbf2(o4, o5); o[3] = packbf2(o6, o7);
            *(u32x4*)((u16*)outU + base) = o;
        } else {
            *(float4*)((float*)outU + base)     = make_float4(o0, o1, o2, o3);
            *(float4*)((float*)outU + base + 4) = make_float4(o4, o5, o6, o7);
        }
    } else {
        ((float4*)usum)[(size_t)wid * 32 + 2 * g]     = make_float4(a[0], a[1], a[2], a[3]);
        ((float4*)usum)[(size_t)wid * 32 + 2 * g + 1] = make_float4(a[4], a[5], a[6], a[7]);
    }
}

extern "C" void kernel_launch(void* const* d_in, const int* in_sizes, int n_in,
                              void* d_out, int out_size, void* d_ws, size_t ws_size,
                              hipStream_t stream) {
    const void* ue  = d_in[1];              // user_emb      [nU,128]
    const void* ee  = d_in[2];              // entity_emb    [nE,128]
    const int*  itr = (const int*)d_in[3];  // inter_edge    [2,Ei]
    const void* iw  = d_in[4];              // inter_edge_w  [Ei]
    const int*  eix = (const int*)d_in[5];  // edge_index    [2,Ee]
    const int*  ety = (const int*)d_in[6];  // edge_type     [Ee]
    const void* rel = d_in[7];              // relation_emb  [10,128]
    const void* wq  = d_in[8];              // W_Q           [128,128]

    const int nU = in_sizes[1] / D;
    const int nE = in_sizes[2] / D;
    const int Ei = in_sizes[4];
    const int Ee = in_sizes[6];
    const int nRel = in_sizes[7] / D;   // 10

    const int* u_idx = itr;            // inter_edge[0] (dest users)
    const int* i_idx = itr + Ei;       // inter_edge[1] (src entities)
    const int* head  = eix;            // edge_index[0] (dest entities)
    const int* tail  = eix + Ee;       // edge_index[1] (src entities)

    char* w = (char*)d_ws;
    auto alloc = [&](size_t bytes) {
        char* p = w;
        w += (bytes + 255) & ~(size_t)255;
        return p;
    };
    int*   flag  = (int*)alloc(256);
    int*  e_off  = (int*)alloc((size_t)(nE + 1) * 4);
    int*  u_off  = (int*)alloc((size_t)(nU + 1) * 4);
    int*  e_pos  = (int*)alloc((size_t)nE * 4);
    int*  u_pos  = (int*)alloc((size_t)nU * 4);
    int*  e_pack = (int*)alloc((size_t)Ee * 4);
    int*  u_item = (int*)alloc((size_t)Ei * 4);
    float* u_wt  = (float*)alloc((size_t)Ei * 4);
    int*  bsumE  = (int*)alloc(64 * 4);
    int*  bsumU  = (int*)alloc(64 * 4);
    u16*  eeb    = (u16*)alloc((size_t)nE * D * 2);
    u16*  wqb    = (u16*)alloc((size_t)D * D * 2);
    u16*  relb   = (u16*)alloc((size_t)nRel * D * 2);
    u16*  eL1    = (u16*)alloc((size_t)nE * D * 2);
    u16*  P      = (u16*)alloc((size_t)nE * D * 2);
    float* usum  = (float*)alloc((size_t)nU * D * 4);

    if ((size_t)(w - (char*)d_ws) > ws_size) {
        // Workspace too small. Output stays harness-zeroed.
        return;
    }

    sniff_k<<<1, 64, 0, stream>>>((const u16*)ue, flag);

    // canonical bf16 copies of hot read-only tensors
    convert_k<<<(nE * D + 255) / 256, 256, 0, stream>>>(ee, eeb, nE * D, flag);
    convert_k<<<(D * D + 255) / 256, 256, 0, stream>>>(wq, wqb, D * D, flag);
    convert_k<<<(nRel * D + 255) / 256, 256, 0, stream>>>(rel, relb, nRel * D, flag);

    // ---- CSR build (structure identical across layers) ----
    const int nbE = (nE + 1023) / 1024;
    const int nbU = (nU + 1023) / 1024;
    zero_k<<<(nE + 1 + 255) / 256, 256, 0, stream>>>(e_off, nE + 1);
    zero_k<<<(nU + 1 + 255) / 256, 256, 0, stream>>>(u_off, nU + 1);
    hist_k<<<(Ee + 255) / 256, 256, 0, stream>>>(head, Ee, nE, e_off);
    hist_k<<<(Ei + 255) / 256, 256, 0, stream>>>(u_idx, Ei, nU, u_off);
    block_sum_k<<<nbE, 256, 0, stream>>>(e_off, nE, bsumE);
    block_sum_k<<<nbU, 256, 0, stream>>>(u_off, nU, bsumU);
    scan_bsums_k<<<1, 64, 0, stream>>>(bsumE, nbE);
    scan_bsums_k<<<1, 64, 0, stream>>>(bsumU, nbU);
    block_scan_k<<<nbE, 256, 0, stream>>>(e_off, nE, bsumE);
    block_scan_k<<<nbU, 256, 0, stream>>>(u_off, nU, bsumU);
    copy_k<<<(nE + 255) / 256, 256, 0, stream>>>(e_off, e_pos, nE);
    copy_k<<<(nU + 255) / 256, 256, 0, stream>>>(u_off, u_pos, nU);
    scatter_e<<<(Ee + 255) / 256, 256, 0, stream>>>(head, tail, ety, Ee, nE, nE,
                                                    e_pos, e_pack);
    scatter_u<<<(Ei + 255) / 256, 256, 0, stream>>>(u_idx, i_idx, iw, Ei, nU, nE,
                                                    u_pos, u_item, u_wt, flag);

    const int entBlocks  = (nE * 64 + 255) / 256;
    const int userBlocks = (nU * 64 + 255) / 256;
    const int gemmBlocks = (nE + GEMM_ROWS - 1) / GEMM_ROWS;

    // ---- layer 1 ----
    gemm_P3<<<gemmBlocks, 256, 0, stream>>>(eeb, wqb, P, nE);
    entity_agg4<<<entBlocks, 256, 0, stream>>>(P, eeb, relb, e_off, e_pack,
                                               eL1, nullptr, 0, 0, nE, flag);
    user_agg4<<<userBlocks, 256, 0, stream>>>(eeb, u_off, u_item, u_wt,
                                              usum, nullptr, nullptr, 0, nU, flag);

    // ---- layer 2 with fused mean epilogue into d_out ----
    gemm_P3<<<gemmBlocks, 256, 0, stream>>>(eL1, wqb, P, nE);
    entity_agg4<<<entBlocks, 256, 0, stream>>>(P, eL1, relb, e_off, e_pack,
                                               d_out, (const u32*)eeb, 1,
                                               (size_t)nU * D, nE, flag);
    user_agg4<<<userBlocks, 256, 0, stream>>>(eL1, u_off, u_item, u_wt,
                                              usum, ue, d_out, 1, nU, flag);
}